// Round 12
// baseline (321.370 us; speedup 1.0000x reference)
//
#include <hip/hip_runtime.h>

#define N_NODES 100000
#define N_EDGES 1600000
#define F 64

#define NBKT 391                  // coarse buckets = ceil(N/256), bucket = id>>8
#define ABLK 512                  // blocks in fused count+scatter pass
#define ECHUNK (N_EDGES / ABLK)   // 3125 edges per block (exact)
#define CAP_B 5120                // fixed bucket capacity (mean 4092, sigma 64 -> +16s)
#define TBLK ((N_NODES + 63) / 64)   // 1563 transform blocks
#define NPAD (TBLK * 64)          // 100032: node rows padded to 64
#define SRC_MASK 0x1FFFF          // low 17 bits hold src (N_NODES < 2^17)
#define P2ROWS 128                // stage-1 reduce output rows
#define PLSZ ((size_t)NPAD * 32)  // bytes per fp8 feature plane (3.2 MB, fits 4MB L2)

typedef unsigned short u16;
typedef unsigned char u8;
typedef __attribute__((ext_vector_type(8))) short bf16x8;  // 8 bf16 = 4 VGPRs
typedef __attribute__((ext_vector_type(4))) float f32x4;
typedef __attribute__((ext_vector_type(2))) float f32x2;

__device__ __forceinline__ float bf2f(u16 h) {
    return __uint_as_float(((unsigned)h) << 16);
}
__device__ __forceinline__ u16 f2bf(float f) {  // round-to-nearest-even
    unsigned u = __float_as_uint(f);
    u += 0x7FFF + ((u >> 16) & 1);
    return (u16)(u >> 16);
}
__device__ __forceinline__ u8 f2f8(float f) {   // fp8 e4m3 via HW cvt (RNE+sat)
    return (u8)(__builtin_amdgcn_cvt_pk_fp8_f32(f, f, 0, false) & 0xff);
}

// ---- fused CSR build: fixed-capacity buckets + global cursor reservation ----

__global__ void init_kernel(int* __restrict__ gcur_d, int* __restrict__ gcur_s) {
    int i = blockIdx.x * 256 + threadIdx.x;
    if (i < NBKT) { gcur_d[i] = i * CAP_B; gcur_s[i] = i * CAP_B; }
}

// One pass with IN-BLOCK COUNTING SORT: stage edges in LDS, dual histogram,
// reserve global ranges, LDS-scan + place into bucket-grouped LDS order,
// then burst-write each (block,bucket) run CONTIGUOUSLY (fixes the 71MB
// partial-line write amplification of the per-edge scattered stores).
__global__ void countscat_kernel(const int* __restrict__ edges,
                                 int* __restrict__ gcur_d,
                                 int* __restrict__ gcur_s,
                                 int* __restrict__ ebuf,
                                 u8* __restrict__ sbuf) {
    __shared__ int sS[ECHUNK], sD[ECHUNK], pe[ECHUNK];   // 3 x 12.5 KB
    __shared__ u16 pb[ECHUNK];                           // 6.25 KB
    __shared__ int hd[NBKT], hs[NBKT], cd[NBKT], cs[NBKT], odx[NBKT], cur[NBKT];
    __shared__ int od[512];
    const int tid = threadIdx.x;
    for (int i = tid; i < NBKT; i += 256) { hd[i] = 0; hs[i] = 0; }
    __syncthreads();
    const int base = blockIdx.x * ECHUNK;
    for (int i = tid; i < ECHUNK; i += 256) {  // single global edge read
        int s = edges[base + i];
        int d = edges[N_EDGES + base + i];
        sS[i] = s; sD[i] = d;
        atomicAdd(&hd[d >> 8], 1);
        atomicAdd(&hs[s >> 8], 1);
    }
    __syncthreads();
    for (int i = tid; i < NBKT; i += 256) {  // reserve global ranges
        cd[i] = atomicAdd(&gcur_d[i], hd[i]);
        cs[i] = atomicAdd(&gcur_s[i], hs[i]);
    }
    // ---- dst pass: scan hd -> place -> burst write ----
    od[tid] = (tid < NBKT) ? hd[tid] : 0;
    od[tid + 256] = (tid + 256 < NBKT) ? hd[tid + 256] : 0;
    __syncthreads();
    for (int o = 1; o < 512; o <<= 1) {
        int t0 = (tid >= o) ? od[tid - o] : 0;
        int t1 = (tid + 256 >= o) ? od[tid + 256 - o] : 0;
        __syncthreads();
        od[tid] += t0; od[tid + 256] += t1;
        __syncthreads();
    }
    for (int i = tid; i < NBKT; i += 256) {
        int ex = od[i] - hd[i];
        odx[i] = ex; cur[i] = ex;
    }
    __syncthreads();
    for (int i = tid; i < ECHUNK; i += 256) {
        int d = sD[i];
        int b = d >> 8;
        int p = atomicAdd(&cur[b], 1);       // LDS atomic only
        pe[p] = ((d & 255) << 17) | sS[i];
        pb[p] = (u16)b;
    }
    __syncthreads();
    for (int k = tid; k < ECHUNK; k += 256) {  // runs contiguous -> coalesced
        int b = pb[k];
        ebuf[cd[b] + (k - odx[b])] = pe[k];
    }
    __syncthreads();
    // ---- src pass (reuse od/odx/cur/pb; payload bytes in pe-as-u8) ----
    od[tid] = (tid < NBKT) ? hs[tid] : 0;
    od[tid + 256] = (tid + 256 < NBKT) ? hs[tid + 256] : 0;
    __syncthreads();
    for (int o = 1; o < 512; o <<= 1) {
        int t0 = (tid >= o) ? od[tid - o] : 0;
        int t1 = (tid + 256 >= o) ? od[tid + 256 - o] : 0;
        __syncthreads();
        od[tid] += t0; od[tid + 256] += t1;
        __syncthreads();
    }
    for (int i = tid; i < NBKT; i += 256) {
        int ex = od[i] - hs[i];
        odx[i] = ex; cur[i] = ex;
    }
    __syncthreads();
    u8* peb = (u8*)pe;
    for (int i = tid; i < ECHUNK; i += 256) {
        int s = sS[i];
        int b = s >> 8;
        int p = atomicAdd(&cur[b], 1);
        peb[p] = (u8)(s & 255);
        pb[p] = (u16)b;
    }
    __syncthreads();
    for (int k = tid; k < ECHUNK; k += 256) {
        int b = pb[k];
        sbuf[cs[b] + (k - odx[b])] = peb[k];
    }
}

// One block per dst bucket: stage packed entries in LDS, count low-8-bit
// nodes, scan, emit row_ptr (strided col base) + rdeg + dst-grouped col.
__global__ void bucket_csr_kernel(const int* __restrict__ ebuf,
                                  const int* __restrict__ gcur_d,
                                  int* __restrict__ row_ptr,
                                  int* __restrict__ rdeg,
                                  int* __restrict__ col) {
    __shared__ int eb[CAP_B];
    __shared__ int hist[256];
    __shared__ int sc[256];
    __shared__ int cur[256];
    const int b = blockIdx.x;
    const int tid = threadIdx.x;
    const int base = b * CAP_B;
    int count = gcur_d[b] - base;
    if (count > CAP_B) count = CAP_B;  // safety (statistically unreachable)
    hist[tid] = 0;
    __syncthreads();
    for (int i = tid; i < count; i += 256) {
        int ed = ebuf[base + i];
        eb[i] = ed;
        atomicAdd(&hist[(ed >> 17) & 255], 1);
    }
    __syncthreads();
    int v = hist[tid];
    sc[tid] = v;
    __syncthreads();
    for (int o = 1; o < 256; o <<= 1) {
        int t = (tid >= o) ? sc[tid - o] : 0;
        __syncthreads();
        sc[tid] += t;
        __syncthreads();
    }
    int ex = sc[tid] - v;  // exclusive
    cur[tid] = ex;
    int node = b * 256 + tid;
    if (node < N_NODES) { row_ptr[node] = base + ex; rdeg[node] = v; }
    __syncthreads();
    for (int i = tid; i < count; i += 256) {
        int ed = eb[i];
        int p = atomicAdd(&cur[(ed >> 17) & 255], 1);  // LDS atomic only
        col[base + p] = ed & SRC_MASK;
    }
}

// One block per src bucket: LDS histogram of the 1-byte local ids -> outdeg.
__global__ void src_hist_kernel(const u8* __restrict__ sbuf,
                                const int* __restrict__ gcur_s,
                                float* __restrict__ outdegf) {
    __shared__ int hist[256];
    const int b = blockIdx.x;
    const int tid = threadIdx.x;
    hist[tid] = 0;
    __syncthreads();
    const int base = b * CAP_B;
    const int end = gcur_s[b];
    for (int i = base + tid; i < end; i += 256)
        atomicAdd(&hist[sbuf[i]], 1);
    __syncthreads();
    int node = b * 256 + tid;
    if (node < N_NODES) outdegf[node] = (float)hist[tid];
}

// x (f32) -> xbf (bf16, MFMA root term) AND xf8 planes (fp8 e4m3, gather
// tables): plane p holds features [32p, 32p+32) of all nodes -> 3.2 MB,
// fits one XCD L2.
__global__ void cast_kernel(const float* __restrict__ x,
                            u16* __restrict__ xbf,
                            u8* __restrict__ xf8) {
    int idx = blockIdx.x * 256 + threadIdx.x;  // over N*F/4 = 1.6M exactly
    float4 v = ((const float4*)x)[idx];
    ushort4 o;
    o.x = f2bf(v.x); o.y = f2bf(v.y); o.z = f2bf(v.z); o.w = f2bf(v.w);
    ((ushort4*)xbf)[idx] = o;
    int n = idx >> 4, j = idx & 15;            // feature quad j of node n
    int pk = __builtin_amdgcn_cvt_pk_fp8_f32(v.x, v.y, 0, false);
    pk = __builtin_amdgcn_cvt_pk_fp8_f32(v.z, v.w, pk, true);
    *(int*)(xf8 + (size_t)(j >> 3) * PLSZ + (size_t)n * 32 + (j & 7) * 4) = pk;
}

// Weight prep: wcatL[n][k] (n-major, bf16) so MFMA B-frag k-values are one
// contiguous 16B load per lane. k<64 -> w_rel[k][n]; k>=64 -> w_root[k-64][n].
__global__ void wprep_kernel(const float* __restrict__ w_rel1,
                             const float* __restrict__ w_root1,
                             const float* __restrict__ w_rel2,
                             const float* __restrict__ w_root2,
                             u16* __restrict__ wcat1,
                             u16* __restrict__ wcat2) {
    int idx = blockIdx.x * 256 + threadIdx.x;  // 2 * 64 * 128 = 16384
    int which = idx >> 13;
    int r = idx & 8191;
    int n = r >> 7, k = r & 127;
    const float* wr = which ? w_rel2 : w_rel1;
    const float* wo = which ? w_root2 : w_root1;
    float v = (k < 64) ? wr[k * 64 + n] : wo[(k - 64) * 64 + n];
    (which ? wcat2 : wcat1)[r] = f2bf(v);
}

// Atomic-free pull gather over ONE fp8 plane (32 B/row): lane (g=l>>3,
// i=l&7) loads uint (4 fp8 feats) of edge e+g; 8 lanes cover the row.
// The 3.2MB plane is L2-resident per XCD. HW cvt fp8->f32, f32 acc,
// cross-g shfl_xor combine, bf16 store into feature range [fbase,fbase+32).
__global__ void gather_kernel(const u8* __restrict__ plane,
                              const int* __restrict__ row_ptr,
                              const int* __restrict__ rdeg,
                              const int* __restrict__ col,
                              u16* __restrict__ aggr_bf,
                              const int fbase) {
    int node = blockIdx.x * 4 + (threadIdx.x >> 6);
    if (node >= N_NODES) return;
    const int l = threadIdx.x & 63;
    const int g = l >> 3;    // edge subgroup 0..7
    const int i = l & 7;     // feature quad: plane features 4i..4i+3
    int beg = row_ptr[node];
    int end = beg + rdeg[node];
    float a0 = 0.f, a1 = 0.f, a2 = 0.f, a3 = 0.f;
    int e = beg;
    for (; e + 15 < end; e += 16) {  // 16 edges/iter: 2 row loads in flight
        int s0 = col[e + g];
        int s1 = col[e + 8 + g];
        unsigned v0 = *(const unsigned*)(plane + (size_t)s0 * 32 + i * 4);
        unsigned v1 = *(const unsigned*)(plane + (size_t)s1 * 32 + i * 4);
        f32x2 p0 = __builtin_amdgcn_cvt_pk_f32_fp8((int)v0, false);
        f32x2 p1 = __builtin_amdgcn_cvt_pk_f32_fp8((int)v0, true);
        f32x2 q0 = __builtin_amdgcn_cvt_pk_f32_fp8((int)v1, false);
        f32x2 q1 = __builtin_amdgcn_cvt_pk_f32_fp8((int)v1, true);
        a0 += p0.x + q0.x;
        a1 += p0.y + q0.y;
        a2 += p1.x + q1.x;
        a3 += p1.y + q1.y;
    }
    if (e + 7 < end) {  // one group of 8
        int s0 = col[e + g];
        unsigned v0 = *(const unsigned*)(plane + (size_t)s0 * 32 + i * 4);
        f32x2 p0 = __builtin_amdgcn_cvt_pk_f32_fp8((int)v0, false);
        f32x2 p1 = __builtin_amdgcn_cvt_pk_f32_fp8((int)v0, true);
        a0 += p0.x; a1 += p0.y; a2 += p1.x; a3 += p1.y;
        e += 8;
    }
    int rem = end - e;  // 0..7
    if (g < rem) {
        int s0 = col[e + g];
        unsigned v0 = *(const unsigned*)(plane + (size_t)s0 * 32 + i * 4);
        f32x2 p0 = __builtin_amdgcn_cvt_pk_f32_fp8((int)v0, false);
        f32x2 p1 = __builtin_amdgcn_cvt_pk_f32_fp8((int)v0, true);
        a0 += p0.x; a1 += p0.y; a2 += p1.x; a3 += p1.y;
    }
    a0 += __shfl_xor(a0, 8, 64); a0 += __shfl_xor(a0, 16, 64); a0 += __shfl_xor(a0, 32, 64);
    a1 += __shfl_xor(a1, 8, 64); a1 += __shfl_xor(a1, 16, 64); a1 += __shfl_xor(a1, 32, 64);
    a2 += __shfl_xor(a2, 8, 64); a2 += __shfl_xor(a2, 16, 64); a2 += __shfl_xor(a2, 32, 64);
    a3 += __shfl_xor(a3, 8, 64); a3 += __shfl_xor(a3, 16, 64); a3 += __shfl_xor(a3, 32, 64);
    if (g == 0) {
        ushort4 o;
        o.x = f2bf(a0); o.y = f2bf(a1); o.z = f2bf(a2); o.w = f2bf(a3);
        *(ushort4*)(aggr_bf + (size_t)node * F + fbase + i * 4) = o;
    }
}

// ---- MFMA transforms: h = relu([aggr|x] @ [w_rel;w_root] + b) ----
// Per block: 64 nodes, 4 waves; wave wv owns m-tile nodes node0..node0+15.
// A-frag (16x16x32 bf16): A[m=lane&15][k=quad*8+j] -> 16B global loads.
// B-frag: B[k=quad*8+j][n=lane&15] from n-major wcat -> 16B global loads.
// C/D: col=lane&15 (fout), row=quad*4+reg (node).  LDS-free.

__global__ void transform1_mfma_kernel(const u16* __restrict__ aggr_bf,
                                       const u16* __restrict__ xbf,
                                       const u16* __restrict__ wcat,
                                       const float* __restrict__ b_rel,
                                       u16* __restrict__ h1bf,
                                       u8* __restrict__ h1f8) {
    const int l = threadIdx.x & 63;
    const int wv = threadIdx.x >> 6;
    const int node0 = blockIdx.x * 64 + wv * 16;
    const int c = l & 15;
    const int quad = l >> 4;

    const size_t arow = (size_t)(node0 + c) * F + quad * 8;  // pad rows: poison, masked below
    bf16x8 a0 = *(const bf16x8*)(aggr_bf + arow);
    bf16x8 a1 = *(const bf16x8*)(aggr_bf + arow + 32);
    bf16x8 a2 = *(const bf16x8*)(xbf + arow);
    bf16x8 a3 = *(const bf16x8*)(xbf + arow + 32);

    f32x4 acc[4];
#pragma unroll
    for (int nt = 0; nt < 4; nt++) {
        const u16* wp = wcat + (size_t)(nt * 16 + c) * 128 + quad * 8;
        bf16x8 b0 = *(const bf16x8*)(wp);
        bf16x8 b1 = *(const bf16x8*)(wp + 32);
        bf16x8 b2 = *(const bf16x8*)(wp + 64);
        bf16x8 b3 = *(const bf16x8*)(wp + 96);
        f32x4 d = {0.f, 0.f, 0.f, 0.f};
        d = __builtin_amdgcn_mfma_f32_16x16x32_bf16(a0, b0, d, 0, 0, 0);
        d = __builtin_amdgcn_mfma_f32_16x16x32_bf16(a1, b1, d, 0, 0, 0);
        d = __builtin_amdgcn_mfma_f32_16x16x32_bf16(a2, b2, d, 0, 0, 0);
        d = __builtin_amdgcn_mfma_f32_16x16x32_bf16(a3, b3, d, 0, 0, 0);
        acc[nt] = d;
    }
#pragma unroll
    for (int nt = 0; nt < 4; nt++) {
        float bias = b_rel[nt * 16 + c];
        int f = nt * 16 + c;
#pragma unroll
        for (int r = 0; r < 4; r++) {
            int node = node0 + quad * 4 + r;
            if (node < N_NODES) {
                float v = fmaxf(acc[nt][r] + bias, 0.f);
                h1bf[(size_t)node * F + f] = f2bf(v);
                h1f8[(size_t)(f >> 5) * PLSZ + (size_t)node * 32 + (f & 31)] = f2f8(v);
            }
        }
    }
}

// Layer-2 MFMA transform fused with the collapsed layer-3 reduction:
// partial[blk] = {sum outdeg*h2, sum h2} over its 64 nodes (h2 never stored).
__global__ void transform2_mfma_kernel(const u16* __restrict__ aggr_bf,
                                       const u16* __restrict__ h1bf,
                                       const u16* __restrict__ wcat,
                                       const float* __restrict__ b_rel,
                                       const float* __restrict__ outdegf,
                                       float* __restrict__ partial) {
    __shared__ float sR1[256], sR2[256];
    const int l = threadIdx.x & 63;
    const int wv = threadIdx.x >> 6;
    const int node0 = blockIdx.x * 64 + wv * 16;
    const int c = l & 15;
    const int quad = l >> 4;

    const size_t arow = (size_t)(node0 + c) * F + quad * 8;
    bf16x8 a0 = *(const bf16x8*)(aggr_bf + arow);
    bf16x8 a1 = *(const bf16x8*)(aggr_bf + arow + 32);
    bf16x8 a2 = *(const bf16x8*)(h1bf + arow);
    bf16x8 a3 = *(const bf16x8*)(h1bf + arow + 32);

    f32x4 acc[4];
#pragma unroll
    for (int nt = 0; nt < 4; nt++) {
        const u16* wp = wcat + (size_t)(nt * 16 + c) * 128 + quad * 8;
        bf16x8 b0 = *(const bf16x8*)(wp);
        bf16x8 b1 = *(const bf16x8*)(wp + 32);
        bf16x8 b2 = *(const bf16x8*)(wp + 64);
        bf16x8 b3 = *(const bf16x8*)(wp + 96);
        f32x4 d = {0.f, 0.f, 0.f, 0.f};
        d = __builtin_amdgcn_mfma_f32_16x16x32_bf16(a0, b0, d, 0, 0, 0);
        d = __builtin_amdgcn_mfma_f32_16x16x32_bf16(a1, b1, d, 0, 0, 0);
        d = __builtin_amdgcn_mfma_f32_16x16x32_bf16(a2, b2, d, 0, 0, 0);
        d = __builtin_amdgcn_mfma_f32_16x16x32_bf16(a3, b3, d, 0, 0, 0);
        acc[nt] = d;
    }

    // rows this lane holds: node0 + quad*4 + r (independent of nt)
    float deg[4], val[4];
#pragma unroll
    for (int r = 0; r < 4; r++) {
        int node = node0 + quad * 4 + r;
        bool v = node < N_NODES;
        deg[r] = v ? outdegf[node] : 0.f;
        val[r] = v ? 1.f : 0.f;
    }
    float s1[4], s2[4];
#pragma unroll
    for (int nt = 0; nt < 4; nt++) {
        float bias = b_rel[nt * 16 + c];
        float t1 = 0.f, t2 = 0.f;
#pragma unroll
        for (int r = 0; r < 4; r++) {
            float v = fmaxf(acc[nt][r] + bias, 0.f);
            t1 += deg[r] * v;
            t2 += val[r] * v;
        }
        // combine the 4 quads holding the 16 rows of column nt*16+c
        t1 += __shfl_xor(t1, 16, 64);
        t1 += __shfl_xor(t1, 32, 64);
        t2 += __shfl_xor(t2, 16, 64);
        t2 += __shfl_xor(t2, 32, 64);
        s1[nt] = t1;
        s2[nt] = t2;
    }
    if (quad == 0) {
#pragma unroll
        for (int nt = 0; nt < 4; nt++) {
            sR1[wv * 64 + nt * 16 + c] = s1[nt];
            sR2[wv * 64 + nt * 16 + c] = s2[nt];
        }
    }
    __syncthreads();
    if (threadIdx.x < 64) {
        int f = threadIdx.x;
        float p1 = sR1[f] + sR1[64 + f] + sR1[128 + f] + sR1[192 + f];
        float p2 = sR2[f] + sR2[64 + f] + sR2[128 + f] + sR2[192 + f];
        partial[(size_t)blockIdx.x * 128 + f] = p1;
        partial[(size_t)blockIdx.x * 128 + 64 + f] = p2;
    }
}

// Stage 1: 128 blocks x 256 threads; block b sums rows {b, b+128, ...} of
// partial[TBLK][128] (coalesced).
__global__ void reduce_p1_kernel(const float* __restrict__ partial,
                                 float* __restrict__ partial2) {
    __shared__ float sm[256];
    const int f = threadIdx.x & 127;
    const int h = threadIdx.x >> 7;  // 0..1
    const int b = blockIdx.x;        // 0..127
    float s = 0.f;
    for (int k = b + P2ROWS * h; k < TBLK; k += 2 * P2ROWS)
        s += partial[(size_t)k * 128 + f];
    sm[threadIdx.x] = s;
    __syncthreads();
    if (threadIdx.x < 128)
        partial2[(size_t)b * 128 + f] = sm[f] + sm[128 + f];
}

// Stage 2: out = (S1 . w_rel3 + S2 . w_root3)/N + b3 from 128x128 partial2.
__global__ void final2_kernel(const float* __restrict__ partial2,
                              const float* __restrict__ w_rel3,
                              const float* __restrict__ b_rel3,
                              const float* __restrict__ w_root3,
                              float* __restrict__ out) {
    __shared__ float sS[1024];
    __shared__ float sT[128];
    const int t = threadIdx.x;  // 1024 threads
    const int f = t & 127;
    const int g = t >> 7;       // 8 interleaved groups
    float s = 0.f;
    for (int k = g; k < P2ROWS; k += 8) s += partial2[(size_t)k * 128 + f];
    sS[t] = s;
    __syncthreads();
    if (t < 128) {
        float tot = 0.f;
#pragma unroll
        for (int j = 0; j < 8; j++) tot += sS[j * 128 + t];
        sT[t] = tot;
    }
    __syncthreads();
    if (t < 64) {
        float v = sT[t] * w_rel3[t] + sT[64 + t] * w_root3[t];
        for (int off = 32; off > 0; off >>= 1) v += __shfl_down(v, off);
        if (t == 0) out[0] = v * (1.0f / (float)N_NODES) + b_rel3[0];
    }
}

extern "C" void kernel_launch(void* const* d_in, const int* in_sizes, int n_in,
                              void* d_out, int out_size, void* d_ws, size_t ws_size,
                              hipStream_t stream) {
    const float* x       = (const float*)d_in[0];
    const int*   edges   = (const int*)d_in[1];   // [2, E]: src row then dst row
    const float* w_rel1  = (const float*)d_in[2];
    const float* b_rel1  = (const float*)d_in[3];
    const float* w_root1 = (const float*)d_in[4];
    const float* w_rel2  = (const float*)d_in[5];
    const float* b_rel2  = (const float*)d_in[6];
    const float* w_root2 = (const float*)d_in[7];
    const float* w_rel3  = (const float*)d_in[8];
    const float* b_rel3  = (const float*)d_in[9];
    const float* w_root3 = (const float*)d_in[10];
    float* out = (float*)d_out;

    const size_t nfp = (size_t)NPAD * F;  // padded rows for maskless MFMA A-loads
    char* p = (char*)d_ws;
    u16*   xbf      = (u16*)p;                p += nfp * 2;                 // 12.8 MB
    u16*   h1bf     = (u16*)p;                p += nfp * 2;                 // 12.8 MB
    u16*   aggr_bf  = (u16*)p;                p += nfp * 2;                 // 12.8 MB
    u8*    xf8      = (u8*)p;                 p += nfp;                     // 6.4 MB (2 planes)
    u8*    h1f8     = (u8*)p;                 p += nfp;                     // 6.4 MB (2 planes)
    int*   row_ptr  = (int*)p;                p += (size_t)N_NODES * 4;     // 0.4 MB
    int*   rdeg     = (int*)p;                p += (size_t)N_NODES * 4;     // 0.4 MB
    int*   col      = (int*)p;                p += (size_t)NBKT * CAP_B * 4; // 8.0 MB
    int*   ebuf     = (int*)p;                p += (size_t)NBKT * CAP_B * 4; // 8.0 MB
    int*   gcur_d   = (int*)p;                p += NBKT * 4;
    int*   gcur_s   = (int*)p;                p += NBKT * 4 + 8;            // pad align
    float* outdegf  = (float*)p;              p += (size_t)N_NODES * 4;     // 0.4 MB
    float* partial  = (float*)p;              p += (size_t)TBLK * 128 * 4;  // 0.8 MB
    float* partial2 = (float*)p;              p += (size_t)P2ROWS * 128 * 4;
    u16*   wcat1    = (u16*)p;                p += 64 * 128 * 2;            // 16 KB
    u16*   wcat2    = (u16*)p;                p += 64 * 128 * 2;            // 16 KB
    u8*    sbuf     = (u8*)p;                                              // 2.0 MB

    // ---- fused counting sort: dst-CSR + src outdeg (no scans needed) ----
    init_kernel<<<(NBKT + 255) / 256, 256, 0, stream>>>(gcur_d, gcur_s);
    countscat_kernel<<<ABLK, 256, 0, stream>>>(edges, gcur_d, gcur_s, ebuf, sbuf);
    bucket_csr_kernel<<<NBKT, 256, 0, stream>>>(ebuf, gcur_d, row_ptr, rdeg, col);
    src_hist_kernel<<<NBKT, 256, 0, stream>>>(sbuf, gcur_s, outdegf);

    // ---- features to bf16 (MFMA) + fp8 planes (gather); weights to bf16 ----
    cast_kernel<<<(N_NODES * F / 4 + 255) / 256, 256, 0, stream>>>(x, xbf, xf8);
    wprep_kernel<<<64, 256, 0, stream>>>(w_rel1, w_root1, w_rel2, w_root2, wcat1, wcat2);

    const int gather_blocks = (N_NODES + 3) / 4;  // 25000: high TLP

    // layer 1 (two L2-resident plane passes)
    gather_kernel<<<gather_blocks, 256, 0, stream>>>(xf8, row_ptr, rdeg, col, aggr_bf, 0);
    gather_kernel<<<gather_blocks, 256, 0, stream>>>(xf8 + PLSZ, row_ptr, rdeg, col, aggr_bf, 32);
    transform1_mfma_kernel<<<TBLK, 256, 0, stream>>>(aggr_bf, xbf, wcat1, b_rel1,
                                                     h1bf, h1f8);

    // layer 2 + collapsed layer 3 (h2 never materialized)
    gather_kernel<<<gather_blocks, 256, 0, stream>>>(h1f8, row_ptr, rdeg, col, aggr_bf, 0);
    gather_kernel<<<gather_blocks, 256, 0, stream>>>(h1f8 + PLSZ, row_ptr, rdeg, col, aggr_bf, 32);
    transform2_mfma_kernel<<<TBLK, 256, 0, stream>>>(aggr_bf, h1bf, wcat2, b_rel2,
                                                     outdegf, partial);

    // two-stage partial reduction
    reduce_p1_kernel<<<P2ROWS, 256, 0, stream>>>(partial, partial2);
    final2_kernel<<<1, 1024, 0, stream>>>(partial2, w_rel3, b_rel3, w_root3, out);
}

// Round 13
// 283.940 us; speedup vs baseline: 1.1318x; 1.1318x over previous
//
#include <hip/hip_runtime.h>

#define N_NODES 100000
#define N_EDGES 1600000
#define F 64

#define NBKT 391                  // coarse buckets = ceil(N/256), bucket = id>>8
#define ABLK 512                  // blocks in fused count+scatter pass
#define ECHUNK (N_EDGES / ABLK)   // 3125 edges per block (exact)
#define CAP_B 5120                // fixed bucket capacity (mean 4092, sigma 64 -> +16s)
#define TBLK ((N_NODES + 63) / 64)   // 1563 transform blocks
#define NPAD (TBLK * 64)          // 100032: node rows padded to 64
#define SRC_MASK 0x1FFFF          // low 17 bits hold src (N_NODES < 2^17)
#define P2ROWS 128                // stage-1 reduce output rows

typedef unsigned short u16;
typedef unsigned char u8;
typedef __attribute__((ext_vector_type(8))) short bf16x8;  // 8 bf16 = 4 VGPRs
typedef __attribute__((ext_vector_type(4))) float f32x4;
typedef __attribute__((ext_vector_type(2))) float f32x2;

__device__ __forceinline__ float bf2f(u16 h) {
    return __uint_as_float(((unsigned)h) << 16);
}
__device__ __forceinline__ u16 f2bf(float f) {  // round-to-nearest-even
    unsigned u = __float_as_uint(f);
    u += 0x7FFF + ((u >> 16) & 1);
    return (u16)(u >> 16);
}
__device__ __forceinline__ u8 f2f8(float f) {   // fp8 e4m3 via HW cvt (RNE+sat)
    return (u8)(__builtin_amdgcn_cvt_pk_fp8_f32(f, f, 0, false) & 0xff);
}

// ---- fused CSR build: fixed-capacity buckets + global cursor reservation ----

__global__ void init_kernel(int* __restrict__ gcur_d, int* __restrict__ gcur_s) {
    int i = blockIdx.x * 256 + threadIdx.x;
    if (i < NBKT) { gcur_d[i] = i * CAP_B; gcur_s[i] = i * CAP_B; }
}

// One pass with IN-BLOCK COUNTING SORT (kept from R12 — verified win: the
// burst-contiguous writes fixed the 71MB partial-line write amplification).
__global__ void countscat_kernel(const int* __restrict__ edges,
                                 int* __restrict__ gcur_d,
                                 int* __restrict__ gcur_s,
                                 int* __restrict__ ebuf,
                                 u8* __restrict__ sbuf) {
    __shared__ int sS[ECHUNK], sD[ECHUNK], pe[ECHUNK];   // 3 x 12.5 KB
    __shared__ u16 pb[ECHUNK];                           // 6.25 KB
    __shared__ int hd[NBKT], hs[NBKT], cd[NBKT], cs[NBKT], odx[NBKT], cur[NBKT];
    __shared__ int od[512];
    const int tid = threadIdx.x;
    for (int i = tid; i < NBKT; i += 256) { hd[i] = 0; hs[i] = 0; }
    __syncthreads();
    const int base = blockIdx.x * ECHUNK;
    for (int i = tid; i < ECHUNK; i += 256) {  // single global edge read
        int s = edges[base + i];
        int d = edges[N_EDGES + base + i];
        sS[i] = s; sD[i] = d;
        atomicAdd(&hd[d >> 8], 1);
        atomicAdd(&hs[s >> 8], 1);
    }
    __syncthreads();
    for (int i = tid; i < NBKT; i += 256) {  // reserve global ranges
        cd[i] = atomicAdd(&gcur_d[i], hd[i]);
        cs[i] = atomicAdd(&gcur_s[i], hs[i]);
    }
    // ---- dst pass: scan hd -> place -> burst write ----
    od[tid] = (tid < NBKT) ? hd[tid] : 0;
    od[tid + 256] = (tid + 256 < NBKT) ? hd[tid + 256] : 0;
    __syncthreads();
    for (int o = 1; o < 512; o <<= 1) {
        int t0 = (tid >= o) ? od[tid - o] : 0;
        int t1 = (tid + 256 >= o) ? od[tid + 256 - o] : 0;
        __syncthreads();
        od[tid] += t0; od[tid + 256] += t1;
        __syncthreads();
    }
    for (int i = tid; i < NBKT; i += 256) {
        int ex = od[i] - hd[i];
        odx[i] = ex; cur[i] = ex;
    }
    __syncthreads();
    for (int i = tid; i < ECHUNK; i += 256) {
        int d = sD[i];
        int b = d >> 8;
        int p = atomicAdd(&cur[b], 1);       // LDS atomic only
        pe[p] = ((d & 255) << 17) | sS[i];
        pb[p] = (u16)b;
    }
    __syncthreads();
    for (int k = tid; k < ECHUNK; k += 256) {  // runs contiguous -> coalesced
        int b = pb[k];
        ebuf[cd[b] + (k - odx[b])] = pe[k];
    }
    __syncthreads();
    // ---- src pass (reuse od/odx/cur/pb; payload bytes in pe-as-u8) ----
    od[tid] = (tid < NBKT) ? hs[tid] : 0;
    od[tid + 256] = (tid + 256 < NBKT) ? hs[tid + 256] : 0;
    __syncthreads();
    for (int o = 1; o < 512; o <<= 1) {
        int t0 = (tid >= o) ? od[tid - o] : 0;
        int t1 = (tid + 256 >= o) ? od[tid + 256 - o] : 0;
        __syncthreads();
        od[tid] += t0; od[tid + 256] += t1;
        __syncthreads();
    }
    for (int i = tid; i < NBKT; i += 256) {
        int ex = od[i] - hs[i];
        odx[i] = ex; cur[i] = ex;
    }
    __syncthreads();
    u8* peb = (u8*)pe;
    for (int i = tid; i < ECHUNK; i += 256) {
        int s = sS[i];
        int b = s >> 8;
        int p = atomicAdd(&cur[b], 1);
        peb[p] = (u8)(s & 255);
        pb[p] = (u16)b;
    }
    __syncthreads();
    for (int k = tid; k < ECHUNK; k += 256) {
        int b = pb[k];
        sbuf[cs[b] + (k - odx[b])] = peb[k];
    }
}

// One block per dst bucket: stage packed entries in LDS, count low-8-bit
// nodes, scan, emit row_ptr (strided col base) + rdeg + dst-grouped col.
__global__ void bucket_csr_kernel(const int* __restrict__ ebuf,
                                  const int* __restrict__ gcur_d,
                                  int* __restrict__ row_ptr,
                                  int* __restrict__ rdeg,
                                  int* __restrict__ col) {
    __shared__ int eb[CAP_B];
    __shared__ int hist[256];
    __shared__ int sc[256];
    __shared__ int cur[256];
    const int b = blockIdx.x;
    const int tid = threadIdx.x;
    const int base = b * CAP_B;
    int count = gcur_d[b] - base;
    if (count > CAP_B) count = CAP_B;  // safety (statistically unreachable)
    hist[tid] = 0;
    __syncthreads();
    for (int i = tid; i < count; i += 256) {
        int ed = ebuf[base + i];
        eb[i] = ed;
        atomicAdd(&hist[(ed >> 17) & 255], 1);
    }
    __syncthreads();
    int v = hist[tid];
    sc[tid] = v;
    __syncthreads();
    for (int o = 1; o < 256; o <<= 1) {
        int t = (tid >= o) ? sc[tid - o] : 0;
        __syncthreads();
        sc[tid] += t;
        __syncthreads();
    }
    int ex = sc[tid] - v;  // exclusive
    cur[tid] = ex;
    int node = b * 256 + tid;
    if (node < N_NODES) { row_ptr[node] = base + ex; rdeg[node] = v; }
    __syncthreads();
    for (int i = tid; i < count; i += 256) {
        int ed = eb[i];
        int p = atomicAdd(&cur[(ed >> 17) & 255], 1);  // LDS atomic only
        col[base + p] = ed & SRC_MASK;
    }
}

// One block per src bucket: LDS histogram of the 1-byte local ids -> outdeg.
__global__ void src_hist_kernel(const u8* __restrict__ sbuf,
                                const int* __restrict__ gcur_s,
                                float* __restrict__ outdegf) {
    __shared__ int hist[256];
    const int b = blockIdx.x;
    const int tid = threadIdx.x;
    hist[tid] = 0;
    __syncthreads();
    const int base = b * CAP_B;
    const int end = gcur_s[b];
    for (int i = base + tid; i < end; i += 256)
        atomicAdd(&hist[sbuf[i]], 1);
    __syncthreads();
    int node = b * 256 + tid;
    if (node < N_NODES) outdegf[node] = (float)hist[tid];
}

// x (f32) -> xbf (bf16, MFMA root term) AND xf8 (fp8 e4m3 flat rows,
// gather table, 64 B/row — R11 layout, re-verified best).
__global__ void cast_kernel(const float* __restrict__ x,
                            u16* __restrict__ xbf,
                            u8* __restrict__ xf8) {
    int i = blockIdx.x * 256 + threadIdx.x;  // over N*F/4 = 1.6M exactly
    float4 v = ((const float4*)x)[i];
    ushort4 o;
    o.x = f2bf(v.x); o.y = f2bf(v.y); o.z = f2bf(v.z); o.w = f2bf(v.w);
    ((ushort4*)xbf)[i] = o;
    int pk = __builtin_amdgcn_cvt_pk_fp8_f32(v.x, v.y, 0, false);
    pk = __builtin_amdgcn_cvt_pk_fp8_f32(v.z, v.w, pk, true);
    ((int*)xf8)[i] = pk;
}

// Weight prep: wcatL[n][k] (n-major, bf16) so MFMA B-frag k-values are one
// contiguous 16B load per lane. k<64 -> w_rel[k][n]; k>=64 -> w_root[k-64][n].
__global__ void wprep_kernel(const float* __restrict__ w_rel1,
                             const float* __restrict__ w_root1,
                             const float* __restrict__ w_rel2,
                             const float* __restrict__ w_root2,
                             u16* __restrict__ wcat1,
                             u16* __restrict__ wcat2) {
    int idx = blockIdx.x * 256 + threadIdx.x;  // 2 * 64 * 128 = 16384
    int which = idx >> 13;
    int r = idx & 8191;
    int n = r >> 7, k = r & 127;
    const float* wr = which ? w_rel2 : w_rel1;
    const float* wo = which ? w_root2 : w_root1;
    float v = (k < 64) ? wr[k * 64 + n] : wo[(k - 64) * 64 + n];
    (which ? wcat2 : wcat1)[r] = f2bf(v);
}

// Atomic-free pull gather over fp8 rows (64 B/row): lane (g=l>>4, i=l&15)
// loads uint (4 fp8 features) of edge e+g; 16 lanes cover the whole row.
// HW cvt fp8->f32, f32 accumulate, cross-g shfl_xor combine, bf16 store.
// (R11 form — single pass per layer; the R12 plane-split regressed.)
__global__ void gather_kernel(const u8* __restrict__ feat8,
                              const int* __restrict__ row_ptr,
                              const int* __restrict__ rdeg,
                              const int* __restrict__ col,
                              u16* __restrict__ aggr_bf) {
    int node = blockIdx.x * 4 + (threadIdx.x >> 6);
    if (node >= N_NODES) return;
    const int l = threadIdx.x & 63;
    const int g = l >> 4;    // edge subgroup 0..3
    const int i = l & 15;    // feature quad: features 4i..4i+3
    int beg = row_ptr[node];
    int end = beg + rdeg[node];
    float a0 = 0.f, a1 = 0.f, a2 = 0.f, a3 = 0.f;
    int e = beg;
    for (; e + 7 < end; e += 8) {  // 8 edges/iter: 2 row loads in flight
        int s0 = col[e + g];
        int s1 = col[e + 4 + g];
        unsigned v0 = *(const unsigned*)(feat8 + (size_t)s0 * F + i * 4);
        unsigned v1 = *(const unsigned*)(feat8 + (size_t)s1 * F + i * 4);
        f32x2 p0 = __builtin_amdgcn_cvt_pk_f32_fp8((int)v0, false);
        f32x2 p1 = __builtin_amdgcn_cvt_pk_f32_fp8((int)v0, true);
        f32x2 q0 = __builtin_amdgcn_cvt_pk_f32_fp8((int)v1, false);
        f32x2 q1 = __builtin_amdgcn_cvt_pk_f32_fp8((int)v1, true);
        a0 += p0.x + q0.x;
        a1 += p0.y + q0.y;
        a2 += p1.x + q1.x;
        a3 += p1.y + q1.y;
    }
    if (e + 3 < end) {  // one group of 4
        int s0 = col[e + g];
        unsigned v0 = *(const unsigned*)(feat8 + (size_t)s0 * F + i * 4);
        f32x2 p0 = __builtin_amdgcn_cvt_pk_f32_fp8((int)v0, false);
        f32x2 p1 = __builtin_amdgcn_cvt_pk_f32_fp8((int)v0, true);
        a0 += p0.x; a1 += p0.y; a2 += p1.x; a3 += p1.y;
        e += 4;
    }
    int rem = end - e;  // 0..3
    if (g < rem) {
        int s0 = col[e + g];
        unsigned v0 = *(const unsigned*)(feat8 + (size_t)s0 * F + i * 4);
        f32x2 p0 = __builtin_amdgcn_cvt_pk_f32_fp8((int)v0, false);
        f32x2 p1 = __builtin_amdgcn_cvt_pk_f32_fp8((int)v0, true);
        a0 += p0.x; a1 += p0.y; a2 += p1.x; a3 += p1.y;
    }
    a0 += __shfl_xor(a0, 16, 64); a0 += __shfl_xor(a0, 32, 64);
    a1 += __shfl_xor(a1, 16, 64); a1 += __shfl_xor(a1, 32, 64);
    a2 += __shfl_xor(a2, 16, 64); a2 += __shfl_xor(a2, 32, 64);
    a3 += __shfl_xor(a3, 16, 64); a3 += __shfl_xor(a3, 32, 64);
    if (g == 0) {
        ushort4 o;
        o.x = f2bf(a0); o.y = f2bf(a1); o.z = f2bf(a2); o.w = f2bf(a3);
        *(ushort4*)(aggr_bf + (size_t)node * F + i * 4) = o;
    }
}

// ---- MFMA transforms: h = relu([aggr|x] @ [w_rel;w_root] + b) ----
// Per block: 64 nodes, 4 waves; wave wv owns m-tile nodes node0..node0+15.
// A-frag (16x16x32 bf16): A[m=lane&15][k=quad*8+j] -> 16B global loads.
// B-frag: B[k=quad*8+j][n=lane&15] from n-major wcat -> 16B global loads.
// C/D: col=lane&15 (fout), row=quad*4+reg (node).  LDS-free.

__global__ void transform1_mfma_kernel(const u16* __restrict__ aggr_bf,
                                       const u16* __restrict__ xbf,
                                       const u16* __restrict__ wcat,
                                       const float* __restrict__ b_rel,
                                       u16* __restrict__ h1bf,
                                       u8* __restrict__ h1f8) {
    const int l = threadIdx.x & 63;
    const int wv = threadIdx.x >> 6;
    const int node0 = blockIdx.x * 64 + wv * 16;
    const int c = l & 15;
    const int quad = l >> 4;

    const size_t arow = (size_t)(node0 + c) * F + quad * 8;  // pad rows: poison, masked below
    bf16x8 a0 = *(const bf16x8*)(aggr_bf + arow);
    bf16x8 a1 = *(const bf16x8*)(aggr_bf + arow + 32);
    bf16x8 a2 = *(const bf16x8*)(xbf + arow);
    bf16x8 a3 = *(const bf16x8*)(xbf + arow + 32);

    f32x4 acc[4];
#pragma unroll
    for (int nt = 0; nt < 4; nt++) {
        const u16* wp = wcat + (size_t)(nt * 16 + c) * 128 + quad * 8;
        bf16x8 b0 = *(const bf16x8*)(wp);
        bf16x8 b1 = *(const bf16x8*)(wp + 32);
        bf16x8 b2 = *(const bf16x8*)(wp + 64);
        bf16x8 b3 = *(const bf16x8*)(wp + 96);
        f32x4 d = {0.f, 0.f, 0.f, 0.f};
        d = __builtin_amdgcn_mfma_f32_16x16x32_bf16(a0, b0, d, 0, 0, 0);
        d = __builtin_amdgcn_mfma_f32_16x16x32_bf16(a1, b1, d, 0, 0, 0);
        d = __builtin_amdgcn_mfma_f32_16x16x32_bf16(a2, b2, d, 0, 0, 0);
        d = __builtin_amdgcn_mfma_f32_16x16x32_bf16(a3, b3, d, 0, 0, 0);
        acc[nt] = d;
    }
#pragma unroll
    for (int nt = 0; nt < 4; nt++) {
        float bias = b_rel[nt * 16 + c];
        int f = nt * 16 + c;
#pragma unroll
        for (int r = 0; r < 4; r++) {
            int node = node0 + quad * 4 + r;
            if (node < N_NODES) {
                float v = fmaxf(acc[nt][r] + bias, 0.f);
                h1bf[(size_t)node * F + f] = f2bf(v);
                h1f8[(size_t)node * F + f] = f2f8(v);
            }
        }
    }
}

// Layer-2 MFMA transform fused with the collapsed layer-3 reduction:
// partial[blk] = {sum outdeg*h2, sum h2} over its 64 nodes (h2 never stored).
__global__ void transform2_mfma_kernel(const u16* __restrict__ aggr_bf,
                                       const u16* __restrict__ h1bf,
                                       const u16* __restrict__ wcat,
                                       const float* __restrict__ b_rel,
                                       const float* __restrict__ outdegf,
                                       float* __restrict__ partial) {
    __shared__ float sR1[256], sR2[256];
    const int l = threadIdx.x & 63;
    const int wv = threadIdx.x >> 6;
    const int node0 = blockIdx.x * 64 + wv * 16;
    const int c = l & 15;
    const int quad = l >> 4;

    const size_t arow = (size_t)(node0 + c) * F + quad * 8;
    bf16x8 a0 = *(const bf16x8*)(aggr_bf + arow);
    bf16x8 a1 = *(const bf16x8*)(aggr_bf + arow + 32);
    bf16x8 a2 = *(const bf16x8*)(h1bf + arow);
    bf16x8 a3 = *(const bf16x8*)(h1bf + arow + 32);

    f32x4 acc[4];
#pragma unroll
    for (int nt = 0; nt < 4; nt++) {
        const u16* wp = wcat + (size_t)(nt * 16 + c) * 128 + quad * 8;
        bf16x8 b0 = *(const bf16x8*)(wp);
        bf16x8 b1 = *(const bf16x8*)(wp + 32);
        bf16x8 b2 = *(const bf16x8*)(wp + 64);
        bf16x8 b3 = *(const bf16x8*)(wp + 96);
        f32x4 d = {0.f, 0.f, 0.f, 0.f};
        d = __builtin_amdgcn_mfma_f32_16x16x32_bf16(a0, b0, d, 0, 0, 0);
        d = __builtin_amdgcn_mfma_f32_16x16x32_bf16(a1, b1, d, 0, 0, 0);
        d = __builtin_amdgcn_mfma_f32_16x16x32_bf16(a2, b2, d, 0, 0, 0);
        d = __builtin_amdgcn_mfma_f32_16x16x32_bf16(a3, b3, d, 0, 0, 0);
        acc[nt] = d;
    }

    // rows this lane holds: node0 + quad*4 + r (independent of nt)
    float deg[4], val[4];
#pragma unroll
    for (int r = 0; r < 4; r++) {
        int node = node0 + quad * 4 + r;
        bool v = node < N_NODES;
        deg[r] = v ? outdegf[node] : 0.f;
        val[r] = v ? 1.f : 0.f;
    }
    float s1[4], s2[4];
#pragma unroll
    for (int nt = 0; nt < 4; nt++) {
        float bias = b_rel[nt * 16 + c];
        float t1 = 0.f, t2 = 0.f;
#pragma unroll
        for (int r = 0; r < 4; r++) {
            float v = fmaxf(acc[nt][r] + bias, 0.f);
            t1 += deg[r] * v;
            t2 += val[r] * v;
        }
        // combine the 4 quads holding the 16 rows of column nt*16+c
        t1 += __shfl_xor(t1, 16, 64);
        t1 += __shfl_xor(t1, 32, 64);
        t2 += __shfl_xor(t2, 16, 64);
        t2 += __shfl_xor(t2, 32, 64);
        s1[nt] = t1;
        s2[nt] = t2;
    }
    if (quad == 0) {
#pragma unroll
        for (int nt = 0; nt < 4; nt++) {
            sR1[wv * 64 + nt * 16 + c] = s1[nt];
            sR2[wv * 64 + nt * 16 + c] = s2[nt];
        }
    }
    __syncthreads();
    if (threadIdx.x < 64) {
        int f = threadIdx.x;
        float p1 = sR1[f] + sR1[64 + f] + sR1[128 + f] + sR1[192 + f];
        float p2 = sR2[f] + sR2[64 + f] + sR2[128 + f] + sR2[192 + f];
        partial[(size_t)blockIdx.x * 128 + f] = p1;
        partial[(size_t)blockIdx.x * 128 + 64 + f] = p2;
    }
}

// Stage 1: 128 blocks x 256 threads; block b sums rows {b, b+128, ...} of
// partial[TBLK][128] (coalesced).
__global__ void reduce_p1_kernel(const float* __restrict__ partial,
                                 float* __restrict__ partial2) {
    __shared__ float sm[256];
    const int f = threadIdx.x & 127;
    const int h = threadIdx.x >> 7;  // 0..1
    const int b = blockIdx.x;        // 0..127
    float s = 0.f;
    for (int k = b + P2ROWS * h; k < TBLK; k += 2 * P2ROWS)
        s += partial[(size_t)k * 128 + f];
    sm[threadIdx.x] = s;
    __syncthreads();
    if (threadIdx.x < 128)
        partial2[(size_t)b * 128 + f] = sm[f] + sm[128 + f];
}

// Stage 2: out = (S1 . w_rel3 + S2 . w_root3)/N + b3 from 128x128 partial2.
__global__ void final2_kernel(const float* __restrict__ partial2,
                              const float* __restrict__ w_rel3,
                              const float* __restrict__ b_rel3,
                              const float* __restrict__ w_root3,
                              float* __restrict__ out) {
    __shared__ float sS[1024];
    __shared__ float sT[128];
    const int t = threadIdx.x;  // 1024 threads
    const int f = t & 127;
    const int g = t >> 7;       // 8 interleaved groups
    float s = 0.f;
    for (int k = g; k < P2ROWS; k += 8) s += partial2[(size_t)k * 128 + f];
    sS[t] = s;
    __syncthreads();
    if (t < 128) {
        float tot = 0.f;
#pragma unroll
        for (int j = 0; j < 8; j++) tot += sS[j * 128 + t];
        sT[t] = tot;
    }
    __syncthreads();
    if (t < 64) {
        float v = sT[t] * w_rel3[t] + sT[64 + t] * w_root3[t];
        for (int off = 32; off > 0; off >>= 1) v += __shfl_down(v, off);
        if (t == 0) out[0] = v * (1.0f / (float)N_NODES) + b_rel3[0];
    }
}

extern "C" void kernel_launch(void* const* d_in, const int* in_sizes, int n_in,
                              void* d_out, int out_size, void* d_ws, size_t ws_size,
                              hipStream_t stream) {
    const float* x       = (const float*)d_in[0];
    const int*   edges   = (const int*)d_in[1];   // [2, E]: src row then dst row
    const float* w_rel1  = (const float*)d_in[2];
    const float* b_rel1  = (const float*)d_in[3];
    const float* w_root1 = (const float*)d_in[4];
    const float* w_rel2  = (const float*)d_in[5];
    const float* b_rel2  = (const float*)d_in[6];
    const float* w_root2 = (const float*)d_in[7];
    const float* w_rel3  = (const float*)d_in[8];
    const float* b_rel3  = (const float*)d_in[9];
    const float* w_root3 = (const float*)d_in[10];
    float* out = (float*)d_out;

    const size_t nfp = (size_t)NPAD * F;  // padded rows for maskless MFMA A-loads
    char* p = (char*)d_ws;
    u16*   xbf      = (u16*)p;                p += nfp * 2;                 // 12.8 MB
    u16*   h1bf     = (u16*)p;                p += nfp * 2;                 // 12.8 MB
    u16*   aggr_bf  = (u16*)p;                p += nfp * 2;                 // 12.8 MB
    u8*    xf8      = (u8*)p;                 p += nfp;                     // 6.4 MB
    u8*    h1f8     = (u8*)p;                 p += nfp;                     // 6.4 MB
    int*   row_ptr  = (int*)p;                p += (size_t)N_NODES * 4;     // 0.4 MB
    int*   rdeg     = (int*)p;                p += (size_t)N_NODES * 4;     // 0.4 MB
    int*   col      = (int*)p;                p += (size_t)NBKT * CAP_B * 4; // 8.0 MB
    int*   ebuf     = (int*)p;                p += (size_t)NBKT * CAP_B * 4; // 8.0 MB
    int*   gcur_d   = (int*)p;                p += NBKT * 4;
    int*   gcur_s   = (int*)p;                p += NBKT * 4 + 8;            // pad align
    float* outdegf  = (float*)p;              p += (size_t)N_NODES * 4;     // 0.4 MB
    float* partial  = (float*)p;              p += (size_t)TBLK * 128 * 4;  // 0.8 MB
    float* partial2 = (float*)p;              p += (size_t)P2ROWS * 128 * 4;
    u16*   wcat1    = (u16*)p;                p += 64 * 128 * 2;            // 16 KB
    u16*   wcat2    = (u16*)p;                p += 64 * 128 * 2;            // 16 KB
    u8*    sbuf     = (u8*)p;                                              // 2.0 MB

    // ---- fused counting sort: dst-CSR + src outdeg (no scans needed) ----
    init_kernel<<<(NBKT + 255) / 256, 256, 0, stream>>>(gcur_d, gcur_s);
    countscat_kernel<<<ABLK, 256, 0, stream>>>(edges, gcur_d, gcur_s, ebuf, sbuf);
    bucket_csr_kernel<<<NBKT, 256, 0, stream>>>(ebuf, gcur_d, row_ptr, rdeg, col);
    src_hist_kernel<<<NBKT, 256, 0, stream>>>(sbuf, gcur_s, outdegf);

    // ---- features to bf16 (MFMA) + fp8 (gather table); weights to bf16 ----
    cast_kernel<<<(N_NODES * F / 4 + 255) / 256, 256, 0, stream>>>(x, xbf, xf8);
    wprep_kernel<<<64, 256, 0, stream>>>(w_rel1, w_root1, w_rel2, w_root2, wcat1, wcat2);

    const int gather_blocks = (N_NODES + 3) / 4;  // 25000: high TLP

    // layer 1
    gather_kernel<<<gather_blocks, 256, 0, stream>>>(xf8, row_ptr, rdeg, col, aggr_bf);
    transform1_mfma_kernel<<<TBLK, 256, 0, stream>>>(aggr_bf, xbf, wcat1, b_rel1,
                                                     h1bf, h1f8);

    // layer 2 + collapsed layer 3 (h2 never materialized)
    gather_kernel<<<gather_blocks, 256, 0, stream>>>(h1f8, row_ptr, rdeg, col, aggr_bf);
    transform2_mfma_kernel<<<TBLK, 256, 0, stream>>>(aggr_bf, h1bf, wcat2, b_rel2,
                                                     outdegf, partial);

    // two-stage partial reduction
    reduce_p1_kernel<<<P2ROWS, 256, 0, stream>>>(partial, partial2);
    final2_kernel<<<1, 1024, 0, stream>>>(partial2, w_rel3, b_rel3, w_root3, out);
}

// Round 14
// 280.024 us; speedup vs baseline: 1.1477x; 1.0140x over previous
//
#include <hip/hip_runtime.h>

#define N_NODES 100000
#define N_EDGES 1600000
#define F 64

#define NBKT 391                  // coarse buckets = ceil(N/256), bucket = id>>8
#define ABLK 512                  // blocks in fused count+scatter pass
#define ECHUNK (N_EDGES / ABLK)   // 3125 edges per block (exact)
#define CAP_B 5120                // fixed bucket capacity (mean 4092, sigma 64 -> +16s)
#define TBLK ((N_NODES + 63) / 64)   // 1563 transform blocks
#define NPAD (TBLK * 64)          // 100032: node rows padded to 64
#define SRC_MASK 0x1FFFF          // low 17 bits hold src (N_NODES < 2^17)
#define P2ROWS 128                // stage-1 reduce output rows

typedef unsigned short u16;
typedef unsigned char u8;
typedef __attribute__((ext_vector_type(8))) short bf16x8;  // 8 bf16 = 4 VGPRs
typedef __attribute__((ext_vector_type(4))) float f32x4;
typedef __attribute__((ext_vector_type(2))) float f32x2;

__device__ __forceinline__ float bf2f(u16 h) {
    return __uint_as_float(((unsigned)h) << 16);
}
__device__ __forceinline__ u16 f2bf(float f) {  // round-to-nearest-even
    unsigned u = __float_as_uint(f);
    u += 0x7FFF + ((u >> 16) & 1);
    return (u16)(u >> 16);
}
__device__ __forceinline__ u8 f2f8(float f) {   // fp8 e4m3 via HW cvt (RNE+sat)
    return (u8)(__builtin_amdgcn_cvt_pk_fp8_f32(f, f, 0, false) & 0xff);
}

// ---- fused CSR build: fixed-capacity buckets + global cursor reservation ----

__global__ void init_kernel(int* __restrict__ gcur_d, int* __restrict__ gcur_s) {
    int i = blockIdx.x * 256 + threadIdx.x;
    if (i < NBKT) { gcur_d[i] = i * CAP_B; gcur_s[i] = i * CAP_B; }
}

// One pass with IN-BLOCK COUNTING SORT (kept from R12 — verified win: the
// burst-contiguous writes fixed the 71MB partial-line write amplification).
__global__ void countscat_kernel(const int* __restrict__ edges,
                                 int* __restrict__ gcur_d,
                                 int* __restrict__ gcur_s,
                                 int* __restrict__ ebuf,
                                 u8* __restrict__ sbuf) {
    __shared__ int sS[ECHUNK], sD[ECHUNK], pe[ECHUNK];   // 3 x 12.5 KB
    __shared__ u16 pb[ECHUNK];                           // 6.25 KB
    __shared__ int hd[NBKT], hs[NBKT], cd[NBKT], cs[NBKT], odx[NBKT], cur[NBKT];
    __shared__ int od[512];
    const int tid = threadIdx.x;
    for (int i = tid; i < NBKT; i += 256) { hd[i] = 0; hs[i] = 0; }
    __syncthreads();
    const int base = blockIdx.x * ECHUNK;
    for (int i = tid; i < ECHUNK; i += 256) {  // single global edge read
        int s = edges[base + i];
        int d = edges[N_EDGES + base + i];
        sS[i] = s; sD[i] = d;
        atomicAdd(&hd[d >> 8], 1);
        atomicAdd(&hs[s >> 8], 1);
    }
    __syncthreads();
    for (int i = tid; i < NBKT; i += 256) {  // reserve global ranges
        cd[i] = atomicAdd(&gcur_d[i], hd[i]);
        cs[i] = atomicAdd(&gcur_s[i], hs[i]);
    }
    // ---- dst pass: scan hd -> place -> burst write ----
    od[tid] = (tid < NBKT) ? hd[tid] : 0;
    od[tid + 256] = (tid + 256 < NBKT) ? hd[tid + 256] : 0;
    __syncthreads();
    for (int o = 1; o < 512; o <<= 1) {
        int t0 = (tid >= o) ? od[tid - o] : 0;
        int t1 = (tid + 256 >= o) ? od[tid + 256 - o] : 0;
        __syncthreads();
        od[tid] += t0; od[tid + 256] += t1;
        __syncthreads();
    }
    for (int i = tid; i < NBKT; i += 256) {
        int ex = od[i] - hd[i];
        odx[i] = ex; cur[i] = ex;
    }
    __syncthreads();
    for (int i = tid; i < ECHUNK; i += 256) {
        int d = sD[i];
        int b = d >> 8;
        int p = atomicAdd(&cur[b], 1);       // LDS atomic only
        pe[p] = ((d & 255) << 17) | sS[i];
        pb[p] = (u16)b;
    }
    __syncthreads();
    for (int k = tid; k < ECHUNK; k += 256) {  // runs contiguous -> coalesced
        int b = pb[k];
        ebuf[cd[b] + (k - odx[b])] = pe[k];
    }
    __syncthreads();
    // ---- src pass (reuse od/odx/cur/pb; payload bytes in pe-as-u8) ----
    od[tid] = (tid < NBKT) ? hs[tid] : 0;
    od[tid + 256] = (tid + 256 < NBKT) ? hs[tid + 256] : 0;
    __syncthreads();
    for (int o = 1; o < 512; o <<= 1) {
        int t0 = (tid >= o) ? od[tid - o] : 0;
        int t1 = (tid + 256 >= o) ? od[tid + 256 - o] : 0;
        __syncthreads();
        od[tid] += t0; od[tid + 256] += t1;
        __syncthreads();
    }
    for (int i = tid; i < NBKT; i += 256) {
        int ex = od[i] - hs[i];
        odx[i] = ex; cur[i] = ex;
    }
    __syncthreads();
    u8* peb = (u8*)pe;
    for (int i = tid; i < ECHUNK; i += 256) {
        int s = sS[i];
        int b = s >> 8;
        int p = atomicAdd(&cur[b], 1);
        peb[p] = (u8)(s & 255);
        pb[p] = (u16)b;
    }
    __syncthreads();
    for (int k = tid; k < ECHUNK; k += 256) {
        int b = pb[k];
        sbuf[cs[b] + (k - odx[b])] = peb[k];
    }
}

// One block per dst bucket: stage packed entries in LDS, count low-8-bit
// nodes, scan, emit row_ptr (strided col base) + rdeg + dst-grouped col.
__global__ void bucket_csr_kernel(const int* __restrict__ ebuf,
                                  const int* __restrict__ gcur_d,
                                  int* __restrict__ row_ptr,
                                  int* __restrict__ rdeg,
                                  int* __restrict__ col) {
    __shared__ int eb[CAP_B];
    __shared__ int hist[256];
    __shared__ int sc[256];
    __shared__ int cur[256];
    const int b = blockIdx.x;
    const int tid = threadIdx.x;
    const int base = b * CAP_B;
    int count = gcur_d[b] - base;
    if (count > CAP_B) count = CAP_B;  // safety (statistically unreachable)
    hist[tid] = 0;
    __syncthreads();
    for (int i = tid; i < count; i += 256) {
        int ed = ebuf[base + i];
        eb[i] = ed;
        atomicAdd(&hist[(ed >> 17) & 255], 1);
    }
    __syncthreads();
    int v = hist[tid];
    sc[tid] = v;
    __syncthreads();
    for (int o = 1; o < 256; o <<= 1) {
        int t = (tid >= o) ? sc[tid - o] : 0;
        __syncthreads();
        sc[tid] += t;
        __syncthreads();
    }
    int ex = sc[tid] - v;  // exclusive
    cur[tid] = ex;
    int node = b * 256 + tid;
    if (node < N_NODES) { row_ptr[node] = base + ex; rdeg[node] = v; }
    __syncthreads();
    for (int i = tid; i < count; i += 256) {
        int ed = eb[i];
        int p = atomicAdd(&cur[(ed >> 17) & 255], 1);  // LDS atomic only
        col[base + p] = ed & SRC_MASK;
    }
}

// One block per src bucket: LDS histogram of the 1-byte local ids -> outdeg.
__global__ void src_hist_kernel(const u8* __restrict__ sbuf,
                                const int* __restrict__ gcur_s,
                                float* __restrict__ outdegf) {
    __shared__ int hist[256];
    const int b = blockIdx.x;
    const int tid = threadIdx.x;
    hist[tid] = 0;
    __syncthreads();
    const int base = b * CAP_B;
    const int end = gcur_s[b];
    for (int i = base + tid; i < end; i += 256)
        atomicAdd(&hist[sbuf[i]], 1);
    __syncthreads();
    int node = b * 256 + tid;
    if (node < N_NODES) outdegf[node] = (float)hist[tid];
}

// x (f32) -> xbf (bf16, MFMA root term) AND xf8 (fp8 e4m3 flat rows).
__global__ void cast_kernel(const float* __restrict__ x,
                            u16* __restrict__ xbf,
                            u8* __restrict__ xf8) {
    int i = blockIdx.x * 256 + threadIdx.x;  // over N*F/4 = 1.6M exactly
    float4 v = ((const float4*)x)[i];
    ushort4 o;
    o.x = f2bf(v.x); o.y = f2bf(v.y); o.z = f2bf(v.z); o.w = f2bf(v.w);
    ((ushort4*)xbf)[i] = o;
    int pk = __builtin_amdgcn_cvt_pk_fp8_f32(v.x, v.y, 0, false);
    pk = __builtin_amdgcn_cvt_pk_fp8_f32(v.z, v.w, pk, true);
    ((int*)xf8)[i] = pk;
}

// Weight prep: wcatL[n][k] (n-major, bf16) so MFMA B-frag k-values are one
// contiguous 16B load per lane. k<64 -> w_rel[k][n]; k>=64 -> w_root[k-64][n].
__global__ void wprep_kernel(const float* __restrict__ w_rel1,
                             const float* __restrict__ w_root1,
                             const float* __restrict__ w_rel2,
                             const float* __restrict__ w_root2,
                             u16* __restrict__ wcat1,
                             u16* __restrict__ wcat2) {
    int idx = blockIdx.x * 256 + threadIdx.x;  // 2 * 64 * 128 = 16384
    int which = idx >> 13;
    int r = idx & 8191;
    int n = r >> 7, k = r & 127;
    const float* wr = which ? w_rel2 : w_rel1;
    const float* wo = which ? w_root2 : w_root1;
    float v = (k < 64) ? wr[k * 64 + n] : wo[(k - 64) * 64 + n];
    (which ? wcat2 : wcat1)[r] = f2bf(v);
}

// Atomic-free pull gather over fp8 rows (64 B/row), DEEP-MLP version:
// - col list loaded ONCE coalesced (lane l -> col[beg+l]), src indices
//   distributed via __shfl (VALU) instead of per-chunk broadcast loads.
// - 16 edges per iteration -> 4 independent feat loads in flight (was 2).
// lane (g=l>>4, i=l&15): loads uint (4 fp8 feats) of edge e+g.
__global__ void gather_kernel(const u8* __restrict__ feat8,
                              const int* __restrict__ row_ptr,
                              const int* __restrict__ rdeg,
                              const int* __restrict__ col,
                              u16* __restrict__ aggr_bf) {
    int node = blockIdx.x * 4 + (threadIdx.x >> 6);
    if (node >= N_NODES) return;
    const int l = threadIdx.x & 63;
    const int g = l >> 4;    // edge subgroup 0..3
    const int i = l & 15;    // feature quad: features 4i..4i+3
    const int beg = row_ptr[node];
    const int deg = rdeg[node];
    float a0 = 0.f, a1 = 0.f, a2 = 0.f, a3 = 0.f;
    for (int base = 0; base < deg; base += 64) {
        const int cnt = min(deg - base, 64);
        int colv = (l < cnt) ? col[beg + base + l] : 0;  // coalesced, 1 instr
        int e = 0;
        for (; e + 15 < cnt; e += 16) {  // 4 feat loads in flight
            int s0 = __shfl(colv, e + g, 64);
            int s1 = __shfl(colv, e + 4 + g, 64);
            int s2 = __shfl(colv, e + 8 + g, 64);
            int s3 = __shfl(colv, e + 12 + g, 64);
            unsigned v0 = *(const unsigned*)(feat8 + (size_t)s0 * F + i * 4);
            unsigned v1 = *(const unsigned*)(feat8 + (size_t)s1 * F + i * 4);
            unsigned v2 = *(const unsigned*)(feat8 + (size_t)s2 * F + i * 4);
            unsigned v3 = *(const unsigned*)(feat8 + (size_t)s3 * F + i * 4);
            f32x2 p0 = __builtin_amdgcn_cvt_pk_f32_fp8((int)v0, false);
            f32x2 p1 = __builtin_amdgcn_cvt_pk_f32_fp8((int)v0, true);
            f32x2 q0 = __builtin_amdgcn_cvt_pk_f32_fp8((int)v1, false);
            f32x2 q1 = __builtin_amdgcn_cvt_pk_f32_fp8((int)v1, true);
            f32x2 r0 = __builtin_amdgcn_cvt_pk_f32_fp8((int)v2, false);
            f32x2 r1 = __builtin_amdgcn_cvt_pk_f32_fp8((int)v2, true);
            f32x2 t0 = __builtin_amdgcn_cvt_pk_f32_fp8((int)v3, false);
            f32x2 t1 = __builtin_amdgcn_cvt_pk_f32_fp8((int)v3, true);
            a0 += (p0.x + q0.x) + (r0.x + t0.x);
            a1 += (p0.y + q0.y) + (r0.y + t0.y);
            a2 += (p1.x + q1.x) + (r1.x + t1.x);
            a3 += (p1.y + q1.y) + (r1.y + t1.y);
        }
        for (; e + 3 < cnt; e += 4) {
            int s0 = __shfl(colv, e + g, 64);
            unsigned v0 = *(const unsigned*)(feat8 + (size_t)s0 * F + i * 4);
            f32x2 p0 = __builtin_amdgcn_cvt_pk_f32_fp8((int)v0, false);
            f32x2 p1 = __builtin_amdgcn_cvt_pk_f32_fp8((int)v0, true);
            a0 += p0.x; a1 += p0.y; a2 += p1.x; a3 += p1.y;
        }
        if (e + g < cnt) {
            int s0 = __shfl(colv, e + g, 64);
            unsigned v0 = *(const unsigned*)(feat8 + (size_t)s0 * F + i * 4);
            f32x2 p0 = __builtin_amdgcn_cvt_pk_f32_fp8((int)v0, false);
            f32x2 p1 = __builtin_amdgcn_cvt_pk_f32_fp8((int)v0, true);
            a0 += p0.x; a1 += p0.y; a2 += p1.x; a3 += p1.y;
        }
    }
    a0 += __shfl_xor(a0, 16, 64); a0 += __shfl_xor(a0, 32, 64);
    a1 += __shfl_xor(a1, 16, 64); a1 += __shfl_xor(a1, 32, 64);
    a2 += __shfl_xor(a2, 16, 64); a2 += __shfl_xor(a2, 32, 64);
    a3 += __shfl_xor(a3, 16, 64); a3 += __shfl_xor(a3, 32, 64);
    if (g == 0) {
        ushort4 o;
        o.x = f2bf(a0); o.y = f2bf(a1); o.z = f2bf(a2); o.w = f2bf(a3);
        *(ushort4*)(aggr_bf + (size_t)node * F + i * 4) = o;
    }
}

// ---- MFMA transforms: h = relu([aggr|x] @ [w_rel;w_root] + b) ----
// Per block: 64 nodes, 4 waves; wave wv owns m-tile nodes node0..node0+15.
// A-frag (16x16x32 bf16): A[m=lane&15][k=quad*8+j] -> 16B global loads.
// B-frag: B[k=quad*8+j][n=lane&15] from n-major wcat -> 16B global loads.
// C/D: col=lane&15 (fout), row=quad*4+reg (node).  LDS-free.

__global__ void transform1_mfma_kernel(const u16* __restrict__ aggr_bf,
                                       const u16* __restrict__ xbf,
                                       const u16* __restrict__ wcat,
                                       const float* __restrict__ b_rel,
                                       u16* __restrict__ h1bf,
                                       u8* __restrict__ h1f8) {
    const int l = threadIdx.x & 63;
    const int wv = threadIdx.x >> 6;
    const int node0 = blockIdx.x * 64 + wv * 16;
    const int c = l & 15;
    const int quad = l >> 4;

    const size_t arow = (size_t)(node0 + c) * F + quad * 8;  // pad rows: poison, masked below
    bf16x8 a0 = *(const bf16x8*)(aggr_bf + arow);
    bf16x8 a1 = *(const bf16x8*)(aggr_bf + arow + 32);
    bf16x8 a2 = *(const bf16x8*)(xbf + arow);
    bf16x8 a3 = *(const bf16x8*)(xbf + arow + 32);

    f32x4 acc[4];
#pragma unroll
    for (int nt = 0; nt < 4; nt++) {
        const u16* wp = wcat + (size_t)(nt * 16 + c) * 128 + quad * 8;
        bf16x8 b0 = *(const bf16x8*)(wp);
        bf16x8 b1 = *(const bf16x8*)(wp + 32);
        bf16x8 b2 = *(const bf16x8*)(wp + 64);
        bf16x8 b3 = *(const bf16x8*)(wp + 96);
        f32x4 d = {0.f, 0.f, 0.f, 0.f};
        d = __builtin_amdgcn_mfma_f32_16x16x32_bf16(a0, b0, d, 0, 0, 0);
        d = __builtin_amdgcn_mfma_f32_16x16x32_bf16(a1, b1, d, 0, 0, 0);
        d = __builtin_amdgcn_mfma_f32_16x16x32_bf16(a2, b2, d, 0, 0, 0);
        d = __builtin_amdgcn_mfma_f32_16x16x32_bf16(a3, b3, d, 0, 0, 0);
        acc[nt] = d;
    }
#pragma unroll
    for (int nt = 0; nt < 4; nt++) {
        float bias = b_rel[nt * 16 + c];
        int f = nt * 16 + c;
#pragma unroll
        for (int r = 0; r < 4; r++) {
            int node = node0 + quad * 4 + r;
            if (node < N_NODES) {
                float v = fmaxf(acc[nt][r] + bias, 0.f);
                h1bf[(size_t)node * F + f] = f2bf(v);
                h1f8[(size_t)node * F + f] = f2f8(v);
            }
        }
    }
}

// Layer-2 MFMA transform fused with the collapsed layer-3 reduction:
// partial[blk] = {sum outdeg*h2, sum h2} over its 64 nodes (h2 never stored).
__global__ void transform2_mfma_kernel(const u16* __restrict__ aggr_bf,
                                       const u16* __restrict__ h1bf,
                                       const u16* __restrict__ wcat,
                                       const float* __restrict__ b_rel,
                                       const float* __restrict__ outdegf,
                                       float* __restrict__ partial) {
    __shared__ float sR1[256], sR2[256];
    const int l = threadIdx.x & 63;
    const int wv = threadIdx.x >> 6;
    const int node0 = blockIdx.x * 64 + wv * 16;
    const int c = l & 15;
    const int quad = l >> 4;

    const size_t arow = (size_t)(node0 + c) * F + quad * 8;
    bf16x8 a0 = *(const bf16x8*)(aggr_bf + arow);
    bf16x8 a1 = *(const bf16x8*)(aggr_bf + arow + 32);
    bf16x8 a2 = *(const bf16x8*)(h1bf + arow);
    bf16x8 a3 = *(const bf16x8*)(h1bf + arow + 32);

    f32x4 acc[4];
#pragma unroll
    for (int nt = 0; nt < 4; nt++) {
        const u16* wp = wcat + (size_t)(nt * 16 + c) * 128 + quad * 8;
        bf16x8 b0 = *(const bf16x8*)(wp);
        bf16x8 b1 = *(const bf16x8*)(wp + 32);
        bf16x8 b2 = *(const bf16x8*)(wp + 64);
        bf16x8 b3 = *(const bf16x8*)(wp + 96);
        f32x4 d = {0.f, 0.f, 0.f, 0.f};
        d = __builtin_amdgcn_mfma_f32_16x16x32_bf16(a0, b0, d, 0, 0, 0);
        d = __builtin_amdgcn_mfma_f32_16x16x32_bf16(a1, b1, d, 0, 0, 0);
        d = __builtin_amdgcn_mfma_f32_16x16x32_bf16(a2, b2, d, 0, 0, 0);
        d = __builtin_amdgcn_mfma_f32_16x16x32_bf16(a3, b3, d, 0, 0, 0);
        acc[nt] = d;
    }

    // rows this lane holds: node0 + quad*4 + r (independent of nt)
    float deg[4], val[4];
#pragma unroll
    for (int r = 0; r < 4; r++) {
        int node = node0 + quad * 4 + r;
        bool v = node < N_NODES;
        deg[r] = v ? outdegf[node] : 0.f;
        val[r] = v ? 1.f : 0.f;
    }
    float s1[4], s2[4];
#pragma unroll
    for (int nt = 0; nt < 4; nt++) {
        float bias = b_rel[nt * 16 + c];
        float t1 = 0.f, t2 = 0.f;
#pragma unroll
        for (int r = 0; r < 4; r++) {
            float v = fmaxf(acc[nt][r] + bias, 0.f);
            t1 += deg[r] * v;
            t2 += val[r] * v;
        }
        // combine the 4 quads holding the 16 rows of column nt*16+c
        t1 += __shfl_xor(t1, 16, 64);
        t1 += __shfl_xor(t1, 32, 64);
        t2 += __shfl_xor(t2, 16, 64);
        t2 += __shfl_xor(t2, 32, 64);
        s1[nt] = t1;
        s2[nt] = t2;
    }
    if (quad == 0) {
#pragma unroll
        for (int nt = 0; nt < 4; nt++) {
            sR1[wv * 64 + nt * 16 + c] = s1[nt];
            sR2[wv * 64 + nt * 16 + c] = s2[nt];
        }
    }
    __syncthreads();
    if (threadIdx.x < 64) {
        int f = threadIdx.x;
        float p1 = sR1[f] + sR1[64 + f] + sR1[128 + f] + sR1[192 + f];
        float p2 = sR2[f] + sR2[64 + f] + sR2[128 + f] + sR2[192 + f];
        partial[(size_t)blockIdx.x * 128 + f] = p1;
        partial[(size_t)blockIdx.x * 128 + 64 + f] = p2;
    }
}

// Stage 1: 128 blocks x 256 threads; block b sums rows {b, b+128, ...} of
// partial[TBLK][128] (coalesced).
__global__ void reduce_p1_kernel(const float* __restrict__ partial,
                                 float* __restrict__ partial2) {
    __shared__ float sm[256];
    const int f = threadIdx.x & 127;
    const int h = threadIdx.x >> 7;  // 0..1
    const int b = blockIdx.x;        // 0..127
    float s = 0.f;
    for (int k = b + P2ROWS * h; k < TBLK; k += 2 * P2ROWS)
        s += partial[(size_t)k * 128 + f];
    sm[threadIdx.x] = s;
    __syncthreads();
    if (threadIdx.x < 128)
        partial2[(size_t)b * 128 + f] = sm[f] + sm[128 + f];
}

// Stage 2: out = (S1 . w_rel3 + S2 . w_root3)/N + b3 from 128x128 partial2.
__global__ void final2_kernel(const float* __restrict__ partial2,
                              const float* __restrict__ w_rel3,
                              const float* __restrict__ b_rel3,
                              const float* __restrict__ w_root3,
                              float* __restrict__ out) {
    __shared__ float sS[1024];
    __shared__ float sT[128];
    const int t = threadIdx.x;  // 1024 threads
    const int f = t & 127;
    const int g = t >> 7;       // 8 interleaved groups
    float s = 0.f;
    for (int k = g; k < P2ROWS; k += 8) s += partial2[(size_t)k * 128 + f];
    sS[t] = s;
    __syncthreads();
    if (t < 128) {
        float tot = 0.f;
#pragma unroll
        for (int j = 0; j < 8; j++) tot += sS[j * 128 + t];
        sT[t] = tot;
    }
    __syncthreads();
    if (t < 64) {
        float v = sT[t] * w_rel3[t] + sT[64 + t] * w_root3[t];
        for (int off = 32; off > 0; off >>= 1) v += __shfl_down(v, off);
        if (t == 0) out[0] = v * (1.0f / (float)N_NODES) + b_rel3[0];
    }
}

extern "C" void kernel_launch(void* const* d_in, const int* in_sizes, int n_in,
                              void* d_out, int out_size, void* d_ws, size_t ws_size,
                              hipStream_t stream) {
    const float* x       = (const float*)d_in[0];
    const int*   edges   = (const int*)d_in[1];   // [2, E]: src row then dst row
    const float* w_rel1  = (const float*)d_in[2];
    const float* b_rel1  = (const float*)d_in[3];
    const float* w_root1 = (const float*)d_in[4];
    const float* w_rel2  = (const float*)d_in[5];
    const float* b_rel2  = (const float*)d_in[6];
    const float* w_root2 = (const float*)d_in[7];
    const float* w_rel3  = (const float*)d_in[8];
    const float* b_rel3  = (const float*)d_in[9];
    const float* w_root3 = (const float*)d_in[10];
    float* out = (float*)d_out;

    const size_t nfp = (size_t)NPAD * F;  // padded rows for maskless MFMA A-loads
    char* p = (char*)d_ws;
    u16*   xbf      = (u16*)p;                p += nfp * 2;                 // 12.8 MB
    u16*   h1bf     = (u16*)p;                p += nfp * 2;                 // 12.8 MB
    u16*   aggr_bf  = (u16*)p;                p += nfp * 2;                 // 12.8 MB
    u8*    xf8      = (u8*)p;                 p += nfp;                     // 6.4 MB
    u8*    h1f8     = (u8*)p;                 p += nfp;                     // 6.4 MB
    int*   row_ptr  = (int*)p;                p += (size_t)N_NODES * 4;     // 0.4 MB
    int*   rdeg     = (int*)p;                p += (size_t)N_NODES * 4;     // 0.4 MB
    int*   col      = (int*)p;                p += (size_t)NBKT * CAP_B * 4; // 8.0 MB
    int*   ebuf     = (int*)p;                p += (size_t)NBKT * CAP_B * 4; // 8.0 MB
    int*   gcur_d   = (int*)p;                p += NBKT * 4;
    int*   gcur_s   = (int*)p;                p += NBKT * 4 + 8;            // pad align
    float* outdegf  = (float*)p;              p += (size_t)N_NODES * 4;     // 0.4 MB
    float* partial  = (float*)p;              p += (size_t)TBLK * 128 * 4;  // 0.8 MB
    float* partial2 = (float*)p;              p += (size_t)P2ROWS * 128 * 4;
    u16*   wcat1    = (u16*)p;                p += 64 * 128 * 2;            // 16 KB
    u16*   wcat2    = (u16*)p;                p += 64 * 128 * 2;            // 16 KB
    u8*    sbuf     = (u8*)p;                                              // 2.0 MB

    // ---- fused counting sort: dst-CSR + src outdeg (no scans needed) ----
    init_kernel<<<(NBKT + 255) / 256, 256, 0, stream>>>(gcur_d, gcur_s);
    countscat_kernel<<<ABLK, 256, 0, stream>>>(edges, gcur_d, gcur_s, ebuf, sbuf);
    bucket_csr_kernel<<<NBKT, 256, 0, stream>>>(ebuf, gcur_d, row_ptr, rdeg, col);
    src_hist_kernel<<<NBKT, 256, 0, stream>>>(sbuf, gcur_s, outdegf);

    // ---- features to bf16 (MFMA) + fp8 (gather table); weights to bf16 ----
    cast_kernel<<<(N_NODES * F / 4 + 255) / 256, 256, 0, stream>>>(x, xbf, xf8);
    wprep_kernel<<<64, 256, 0, stream>>>(w_rel1, w_root1, w_rel2, w_root2, wcat1, wcat2);

    const int gather_blocks = (N_NODES + 3) / 4;  // 25000: high TLP

    // layer 1
    gather_kernel<<<gather_blocks, 256, 0, stream>>>(xf8, row_ptr, rdeg, col, aggr_bf);
    transform1_mfma_kernel<<<TBLK, 256, 0, stream>>>(aggr_bf, xbf, wcat1, b_rel1,
                                                     h1bf, h1f8);

    // layer 2 + collapsed layer 3 (h2 never materialized)
    gather_kernel<<<gather_blocks, 256, 0, stream>>>(h1f8, row_ptr, rdeg, col, aggr_bf);
    transform2_mfma_kernel<<<TBLK, 256, 0, stream>>>(aggr_bf, h1bf, wcat2, b_rel2,
                                                     outdegf, partial);

    // two-stage partial reduction
    reduce_p1_kernel<<<P2ROWS, 256, 0, stream>>>(partial, partial2);
    final2_kernel<<<1, 1024, 0, stream>>>(partial2, w_rel3, b_rel3, w_root3, out);
}